// Round 3
// baseline (129.662 us; speedup 1.0000x reference)
//
#include <hip/hip_runtime.h>
#include <hip/hip_bf16.h>

#define N_  32
#define ND_ 16
#define ED_ 8
#define GD_ 8
#define HN_ 128
#define HE_ 128
#define HG_ 128
#define HC_ 64

typedef __attribute__((ext_vector_type(8))) short short8_t;
typedef __attribute__((ext_vector_type(4))) float f32x4;

#define MFMA16(a, b, c) __builtin_amdgcn_mfma_f32_16x16x32_bf16((a), (b), (c), 0, 0, 0)

__device__ __forceinline__ unsigned short f2bf(float f) {
    unsigned int u = __float_as_uint(f);
    unsigned int r = u + 0x7FFFu + ((u >> 16) & 1u);
    return (unsigned short)(r >> 16);
}
__device__ __forceinline__ float bf2f(unsigned short h) {
    return __uint_as_float(((unsigned int)h) << 16);
}

// ---- workspace layout (ushort elements) ----
#define WNS_HI 0
#define WNS_LO 4096
#define WES_HI 8192
#define WES_LO (8192 + 36864)
#define WS_USHORTS (8192 + 2 * 36864)
#define WS_BYTES (WS_USHORTS * 2)

// Prologue: convert + swizzle weights into B-fragment-major bf16 hi/lo.
// lane l holds B[k = 32*s + 8*(l>>4)+i][col = 16*n + (l&15)]
__global__ void prep_weights(const float* __restrict__ Wn,
                             const float* __restrict__ We,
                             unsigned short* __restrict__ wsp) {
    int gid = blockIdx.x * 256 + threadIdx.x;
    if (gid >= 512 + 4608) return;
    float vals[8];
    unsigned short* dh;
    unsigned short* dl;
    if (gid < 512) {
        int l = gid & 63, n = (gid >> 6) & 7;
        int c = 16 * n + (l & 15);
#pragma unroll
        for (int i = 0; i < 8; ++i) {
            int k = 8 * (l >> 4) + i;
            vals[i] = Wn[k * HN_ + c];
        }
        dh = wsp + WNS_HI + gid * 8;
        dl = wsp + WNS_LO + gid * 8;
    } else {
        int g2 = gid - 512;
        int l = g2 & 63, n = (g2 >> 6) & 7, s = g2 >> 9;   // s in 0..8
        int c = 16 * n + (l & 15);
#pragma unroll
        for (int i = 0; i < 8; ++i) {
            int kl = 8 * (l >> 4) + i;
            int ks;
            if (s == 0)      ks = (kl < 8) ? kl : -1;          // ef rows 0..7
            else if (s <= 4) ks = 8 + (s - 1) * 32 + kl;       // W1: h_node[e]
            else             ks = 136 + (s - 5) * 32 + kl;     // W2: h_node[e+1]
            vals[i] = (ks >= 0) ? We[ks * HE_ + c] : 0.0f;
        }
        dh = wsp + WES_HI + g2 * 8;
        dl = wsp + WES_LO + g2 * 8;
    }
    unsigned short h[8], lo[8];
#pragma unroll
    for (int i = 0; i < 8; ++i) {
        h[i] = f2bf(vals[i]);
        lo[i] = f2bf(vals[i] - bf2f(h[i]));
    }
    *(short8_t*)dh = *(short8_t*)h;
    *(short8_t*)dl = *(short8_t*)lo;
}

#define HNS 136   // s_hn row stride (ushorts): 272B = 17*16 -> conflict-benign b128
#define NIS 40    // s_nin/s_efp row stride: 80B = 5*16
#define HES 132   // s_he f32 row stride

// 2 graphs per block. 4 waves x (4 M-tiles x 2 N-tiles).
__global__ __launch_bounds__(256, 2) void gnn_mfma2(
    const float* __restrict__ gf, const float* __restrict__ nf,
    const float* __restrict__ ef, const void* __restrict__ nmask_raw,
    const float* __restrict__ Wn, const float* __restrict__ bn,
    const float* __restrict__ We, const float* __restrict__ be,
    const float* __restrict__ Ws, const float* __restrict__ bs,
    const float* __restrict__ Wg, const float* __restrict__ bg,
    const float* __restrict__ Wc1, const float* __restrict__ bc1,
    const float* __restrict__ Wc2, const float* __restrict__ bc2,
    const unsigned short* __restrict__ wsp,
    float* __restrict__ out, int Btot)
{
    const int b = blockIdx.x;
    const int t = threadIdx.x;
    const int g1r = 2 * b + 1;
    const int gid0 = 2 * b;
    const int gid1 = (g1r < Btot) ? g1r : (Btot - 1);

    __shared__ __align__(16) unsigned short s_hn_h[2][N_ + 1][HNS];
    __shared__ __align__(16) unsigned short s_hn_l[2][N_ + 1][HNS];
    __shared__ __align__(16) unsigned char u_mem[33792];   // union: {nin,efp} / s_he
    __shared__ __align__(16) float s_efraw[2][N_][ED_];
    __shared__ float s_g[2][GD_];
    __shared__ int   s_mi[2][N_];
    __shared__ float s_emask[2][N_];
    __shared__ __align__(16) float s_bias1[2][HN_];
    __shared__ __align__(16) float s_bias2[2][HE_];
    __shared__ float s_sc[2][N_];
    __shared__ float s_w[2][N_];
    __shared__ __align__(16) float s_tmp[256];
    __shared__ __align__(16) float s_aggf[2][HE_];
    __shared__ __align__(16) float s_hg[2][HG_];
    __shared__ __align__(16) float s_hc[2][HC_];

    typedef unsigned short ninrow_t[NIS];
    ninrow_t* s_nin_h = (ninrow_t*)(u_mem);            // rows: g*32+n (64 rows)
    ninrow_t* s_nin_l = (ninrow_t*)(u_mem + 5120);
    ninrow_t* s_efp_h = (ninrow_t*)(u_mem + 10240);
    ninrow_t* s_efp_l = (ninrow_t*)(u_mem + 15360);
    typedef float herow_t[HES];
    herow_t* s_he = (herow_t*)(u_mem);                 // rows: g*32+e (64 rows)

    // ---- node_mask dtype detection (u8 vs i32), deterministic ----
    const unsigned char* mb = (const unsigned char*)nmask_raw;
    int cnt = __syncthreads_count(mb[t] != 0);
    const bool is_u8 = (cnt > 96);

    // ---- Phase A: loads ----
    if (t < 16) s_g[t >> 3][t & 7] = gf[(t >> 3 ? gid1 : gid0) * GD_ + (t & 7)];
    for (int idx = t; idx < 1024; idx += 256) {        // node feats: 2x32x16
        int g = idx >> 9, rem = idx & 511;
        float v = nf[(g ? gid1 : gid0) * 512 + rem];
        unsigned short h = f2bf(v);
        int r = g * 32 + (rem >> 4), k = rem & 15;
        s_nin_h[r][k] = h;
        s_nin_l[r][k] = f2bf(v - bf2f(h));
    }
    for (int idx = t; idx < 512; idx += 256) {         // raw edges (row31 = 0)
        int g = idx >> 8, rem = idx & 255, e = rem >> 3, k = rem & 7;
        s_efraw[g][e][k] = (e < 31) ? ef[(g ? gid1 : gid0) * 248 + e * 8 + k] : 0.0f;
    }
    for (int idx = t; idx < 2048; idx += 256) {        // efp cols 8..39 zero
        int r = idx >> 5, c = 8 + (idx & 31);
        s_efp_h[r][c] = 0; s_efp_l[r][c] = 0;
    }
    if (t < 16) {                                       // node0 edge_backward zero
        int g = t >> 3, k = t & 7;
        s_nin_h[g * 32][16 + k] = 0; s_nin_l[g * 32][16 + k] = 0;
    }
    for (int idx = t; idx < 2 * HNS; idx += 256) {      // h_node[32] = 0
        int g = (idx >= HNS), c = idx - g * HNS;
        s_hn_h[g][N_][c] = 0; s_hn_l[g][N_][c] = 0;
    }
    if (t < 64) {
        int g = t >> 5, n = t & 31;
        int mv = is_u8 ? (int)mb[(g ? gid1 : gid0) * N_ + n]
                       : ((const int*)nmask_raw)[(g ? gid1 : gid0) * N_ + n];
        s_mi[g][n] = mv;
    }
    __syncthreads();

    // ---- Phase B: edge mask + combined biases ----
    if (t < 64) {
        int g = t >> 5, n = t & 31;
        s_emask[g][n] = (n < 31 && s_mi[g][n] != 0 && s_mi[g][n + 1] != 0) ? 1.0f : 0.0f;
    }
    {
        int g = t >> 7, j = t & 127;
        float v1 = bn[j], v2 = be[j];
#pragma unroll
        for (int k = 0; k < GD_; ++k) {
            v1 += s_g[g][k] * Wn[(ND_ + 2 * ED_ + k) * HN_ + j];
            v2 += s_g[g][k] * We[(ED_ + 2 * HN_ + k) * HE_ + j];
        }
        s_bias1[g][j] = v1;
        s_bias2[g][j] = v2;
    }
    __syncthreads();

    // ---- Phase C: efp fill + nin tail ----
    for (int idx = t; idx < 512; idx += 256) {
        int g = idx >> 8, rem = idx & 255, e = rem >> 3, k = rem & 7;
        int r = g * 32 + e;
        float v = s_efraw[g][e][k];
        unsigned short h = f2bf(v);
        s_efp_h[r][k] = h;
        s_efp_l[r][k] = f2bf(v - bf2f(h));
        float vm = v * s_emask[g][e];
        unsigned short hm = f2bf(vm);
        unsigned short lm = f2bf(vm - bf2f(hm));
        if (e < 31) { s_nin_h[r + 1][16 + k] = hm; s_nin_l[r + 1][16 + k] = lm; }
        s_nin_h[r][24 + k] = hm;
        s_nin_l[r][24 + k] = lm;
    }
    __syncthreads();

    const int w = t >> 6, l = t & 63;
    const int lrow = l & 15;
    const int lk = (l >> 4) * 8;
    const int g4 = (l >> 4) * 4;
    const int c0 = 32 * w + lrow, c1 = c0 + 16;

    // ---- Node MLP (MFMA, K=32) ----
    {
        f32x4 acc[4][2];
#pragma unroll
        for (int mt = 0; mt < 4; ++mt) {
            int g = mt >> 1;
            float b0 = s_bias1[g][c0], b1 = s_bias1[g][c1];
            acc[mt][0] = (f32x4){b0, b0, b0, b0};
            acc[mt][1] = (f32x4){b1, b1, b1, b1};
        }
        const unsigned short* bh = wsp + WNS_HI + (2 * w) * 512 + l * 8;
        const unsigned short* bl = wsp + WNS_LO + (2 * w) * 512 + l * 8;
        short8_t Bh0 = *(const short8_t*)bh;
        short8_t Bl0 = *(const short8_t*)bl;
        short8_t Bh1 = *(const short8_t*)(bh + 512);
        short8_t Bl1 = *(const short8_t*)(bl + 512);
#pragma unroll
        for (int mt = 0; mt < 4; ++mt) {
            int r = (mt >> 1) * 32 + (mt & 1) * 16 + lrow;
            short8_t Ah = *(const short8_t*)&s_nin_h[r][lk];
            short8_t Al = *(const short8_t*)&s_nin_l[r][lk];
            acc[mt][0] = MFMA16(Al, Bh0, acc[mt][0]);
            acc[mt][0] = MFMA16(Ah, Bl0, acc[mt][0]);
            acc[mt][0] = MFMA16(Ah, Bh0, acc[mt][0]);
            acc[mt][1] = MFMA16(Al, Bh1, acc[mt][1]);
            acc[mt][1] = MFMA16(Ah, Bl1, acc[mt][1]);
            acc[mt][1] = MFMA16(Ah, Bh1, acc[mt][1]);
        }
#pragma unroll
        for (int mt = 0; mt < 4; ++mt) {
            int g = mt >> 1, rb = (mt & 1) * 16 + g4;
#pragma unroll
            for (int nt = 0; nt < 2; ++nt) {
                int col = nt ? c1 : c0;
#pragma unroll
                for (int r = 0; r < 4; ++r) {
                    float v = fmaxf(acc[mt][nt][r], 0.0f);
                    unsigned short h = f2bf(v);
                    s_hn_h[g][rb + r][col] = h;
                    s_hn_l[g][rb + r][col] = f2bf(v - bf2f(h));
                }
            }
        }
    }
    __syncthreads();

    // ---- Edge MLP (MFMA, Z-split): he[e] = relu(bias2 + ef@We0 + Z1[e] + Z2[e+1])
    {
        f32x4 acc1[4][2], acc2[4][2];
#pragma unroll
        for (int mt = 0; mt < 4; ++mt) {
            int g = mt >> 1;
            float b0 = s_bias2[g][c0], b1 = s_bias2[g][c1];
            acc1[mt][0] = (f32x4){b0, b0, b0, b0};
            acc1[mt][1] = (f32x4){b1, b1, b1, b1};
            acc2[mt][0] = (f32x4){0.f, 0.f, 0.f, 0.f};
            acc2[mt][1] = (f32x4){0.f, 0.f, 0.f, 0.f};
        }
        // step 0: raw edge features -> acc1
        {
            const unsigned short* bh = wsp + WES_HI + (2 * w) * 512 + l * 8;
            const unsigned short* bl = wsp + WES_LO + (2 * w) * 512 + l * 8;
            short8_t Bh0 = *(const short8_t*)bh;
            short8_t Bl0 = *(const short8_t*)bl;
            short8_t Bh1 = *(const short8_t*)(bh + 512);
            short8_t Bl1 = *(const short8_t*)(bl + 512);
#pragma unroll
            for (int mt = 0; mt < 4; ++mt) {
                int r = (mt >> 1) * 32 + (mt & 1) * 16 + lrow;
                short8_t Ah = *(const short8_t*)&s_efp_h[r][lk];
                short8_t Al = *(const short8_t*)&s_efp_l[r][lk];
                acc1[mt][0] = MFMA16(Al, Bh0, acc1[mt][0]);
                acc1[mt][0] = MFMA16(Ah, Bl0, acc1[mt][0]);
                acc1[mt][0] = MFMA16(Ah, Bh0, acc1[mt][0]);
                acc1[mt][1] = MFMA16(Al, Bh1, acc1[mt][1]);
                acc1[mt][1] = MFMA16(Ah, Bl1, acc1[mt][1]);
                acc1[mt][1] = MFMA16(Ah, Bh1, acc1[mt][1]);
            }
        }
        // steps 1..4: A loaded once, feeds W1 (acc1) and W2 (acc2)
#pragma unroll
        for (int s = 1; s <= 4; ++s) {
            const unsigned short* b1h = wsp + WES_HI + (s * 8 + 2 * w) * 512 + l * 8;
            const unsigned short* b1l = wsp + WES_LO + (s * 8 + 2 * w) * 512 + l * 8;
            const unsigned short* b2h = wsp + WES_HI + ((s + 4) * 8 + 2 * w) * 512 + l * 8;
            const unsigned short* b2l = wsp + WES_LO + ((s + 4) * 8 + 2 * w) * 512 + l * 8;
            short8_t B1h0 = *(const short8_t*)b1h;
            short8_t B1l0 = *(const short8_t*)b1l;
            short8_t B1h1 = *(const short8_t*)(b1h + 512);
            short8_t B1l1 = *(const short8_t*)(b1l + 512);
            short8_t B2h0 = *(const short8_t*)b2h;
            short8_t B2l0 = *(const short8_t*)b2l;
            short8_t B2h1 = *(const short8_t*)(b2h + 512);
            short8_t B2l1 = *(const short8_t*)(b2l + 512);
            int kb = (s - 1) * 32 + lk;
#pragma unroll
            for (int mt = 0; mt < 4; ++mt) {
                int g = mt >> 1, row = (mt & 1) * 16 + lrow;
                short8_t Ah = *(const short8_t*)&s_hn_h[g][row][kb];
                short8_t Al = *(const short8_t*)&s_hn_l[g][row][kb];
                acc1[mt][0] = MFMA16(Al, B1h0, acc1[mt][0]);
                acc1[mt][0] = MFMA16(Ah, B1l0, acc1[mt][0]);
                acc1[mt][0] = MFMA16(Ah, B1h0, acc1[mt][0]);
                acc1[mt][1] = MFMA16(Al, B1h1, acc1[mt][1]);
                acc1[mt][1] = MFMA16(Ah, B1l1, acc1[mt][1]);
                acc1[mt][1] = MFMA16(Ah, B1h1, acc1[mt][1]);
                acc2[mt][0] = MFMA16(Al, B2h0, acc2[mt][0]);
                acc2[mt][0] = MFMA16(Ah, B2l0, acc2[mt][0]);
                acc2[mt][0] = MFMA16(Ah, B2h0, acc2[mt][0]);
                acc2[mt][1] = MFMA16(Al, B2h1, acc2[mt][1]);
                acc2[mt][1] = MFMA16(Ah, B2l1, acc2[mt][1]);
                acc2[mt][1] = MFMA16(Ah, B2h1, acc2[mt][1]);
            }
        }
        // epilogue: he[row] = relu(acc1[row] + Z2[row+1]); Z2[32] (per graph) = 0
        float hev[4][2][4];
#pragma unroll
        for (int mt = 0; mt < 4; ++mt) {
#pragma unroll
            for (int nt = 0; nt < 2; ++nt) {
                float inlane = __shfl(acc2[mt][nt][0], (l + 16) & 63);
                float cross = ((mt & 1) == 0) ? __shfl(acc2[mt + 1][nt][0], l & 15) : 0.0f;
                float s3 = (l < 48) ? inlane : cross;
                hev[mt][nt][0] = fmaxf(acc1[mt][nt][0] + acc2[mt][nt][1], 0.0f);
                hev[mt][nt][1] = fmaxf(acc1[mt][nt][1] + acc2[mt][nt][2], 0.0f);
                hev[mt][nt][2] = fmaxf(acc1[mt][nt][2] + acc2[mt][nt][3], 0.0f);
                hev[mt][nt][3] = fmaxf(acc1[mt][nt][3] + s3, 0.0f);
            }
        }
        __syncthreads();   // all s_efp/s_nin reads done -> safe to overwrite union
#pragma unroll
        for (int mt = 0; mt < 4; ++mt) {
            int g = mt >> 1, rb = (mt & 1) * 16 + g4;
#pragma unroll
            for (int nt = 0; nt < 2; ++nt) {
                int col = nt ? c1 : c0;
#pragma unroll
                for (int r = 0; r < 4; ++r)
                    s_he[g * 32 + rb + r][col] = hev[mt][nt][r];
            }
        }
    }
    __syncthreads();

    // ---- P3: scores (64 edges x 4 lanes) ----
    {
        int c = t & 3, eg = t >> 2;
        int g = eg >> 5, e = eg & 31;
        const float* he = &s_he[g * 32 + e][0];
        float p = 0.0f;
#pragma unroll
        for (int j0 = 0; j0 < 32; j0 += 4) {
            float4 h = *(const float4*)&he[c * 32 + j0];
            float4 wv = *(const float4*)&Ws[c * 32 + j0];
            p += h.x * wv.x + h.y * wv.y + h.z * wv.z + h.w * wv.w;
        }
        p += __shfl_xor(p, 1);
        p += __shfl_xor(p, 2);
        if (c == 0) s_sc[g][e] = p + bs[0];
    }
    __syncthreads();

    // ---- masked softmax (graph g on wave g) ----
    if (t < 128) {
        int g = t >> 6, tt = t & 63;
        float v = -INFINITY;
        if (tt < 31)
            v = s_sc[g][tt] * s_emask[g][tt] + (1.0f - s_emask[g][tt]) * (-1e9f);
        float m = v;
#pragma unroll
        for (int d = 32; d >= 1; d >>= 1) m = fmaxf(m, __shfl_xor(m, d));
        float e_ = (tt < 31) ? expf(v - m) : 0.0f;
        float ssum = e_;
#pragma unroll
        for (int d = 32; d >= 1; d >>= 1) ssum += __shfl_xor(ssum, d);
        if (tt < 32) s_w[g][tt] = (tt < 31) ? (e_ / ssum) : 0.0f;
    }
    __syncthreads();

    // ---- P4: weighted edge pooling ----
    {
        int g = t >> 7, j = t & 127;
        float p = 0.0f;
#pragma unroll
        for (int e = 0; e < 31; ++e)
            p += s_he[g * 32 + e][j] * s_w[g][e];
        s_aggf[g][j] = p;
    }
    __syncthreads();

    // ---- P5: h_glob = relu(agg @ Wg + bg) ----
    {
        int g = t >> 7, j = t & 127;
        float a0 = 0, a1 = 0, a2 = 0, a3 = 0;
#pragma unroll 8
        for (int k = 0; k < 128; k += 4) {
            a0 += s_aggf[g][k]     * Wg[k * HG_ + j];
            a1 += s_aggf[g][k + 1] * Wg[(k + 1) * HG_ + j];
            a2 += s_aggf[g][k + 2] * Wg[(k + 2) * HG_ + j];
            a3 += s_aggf[g][k + 3] * Wg[(k + 3) * HG_ + j];
        }
        s_hg[g][j] = fmaxf(a0 + a1 + a2 + a3 + bg[j], 0.0f);
    }
    __syncthreads();

    // ---- P6: h_cls = relu(h_glob @ Wc1 + bc1) ----
    {
        int g = t >> 7, q = (t >> 6) & 1, j = t & 63;
        float a0 = 0, a1 = 0;
        for (int k = q * 64; k < q * 64 + 64; k += 2) {
            a0 += s_hg[g][k]     * Wc1[k * HC_ + j];
            a1 += s_hg[g][k + 1] * Wc1[(k + 1) * HC_ + j];
        }
        s_tmp[t] = a0 + a1;
    }
    __syncthreads();
    if (t < 128) {
        int g = t >> 6, j = t & 63;
        s_hc[g][j] = fmaxf(s_tmp[g * 128 + j] + s_tmp[g * 128 + 64 + j] + bc1[j], 0.0f);
    }
    __syncthreads();

    // ---- P7: y = h_cls @ Wc2 + bc2 ----
    if (t < 128) {
        int g = t >> 6, tt = t & 63;
        float p = s_hc[g][tt] * Wc2[tt];
#pragma unroll
        for (int d = 32; d >= 1; d >>= 1) p += __shfl_xor(p, d);
        if (tt == 0 && 2 * b + g < Btot) out[2 * b + g] = p + bc2[0];
    }
}

// ======================= fallback: f32 kernel =======================
__device__ __forceinline__ void tile_fma_4x4(
    float acc[4][4], const float* in0, const float* in1, const float* in2,
    const float* in3, int k, const float* __restrict__ W, int wrow, int c4)
{
    float in_[4][4];
    *(float4*)&in_[0][0] = *(const float4*)(in0 + k);
    *(float4*)&in_[1][0] = *(const float4*)(in1 + k);
    *(float4*)&in_[2][0] = *(const float4*)(in2 + k);
    *(float4*)&in_[3][0] = *(const float4*)(in3 + k);
#pragma unroll
    for (int kk = 0; kk < 4; ++kk) {
        float w_[4];
        *(float4*)w_ = *(const float4*)&W[(wrow + kk) * 128 + c4];
#pragma unroll
        for (int r = 0; r < 4; ++r)
#pragma unroll
            for (int c = 0; c < 4; ++c)
                acc[r][c] += in_[r][kk] * w_[c];
    }
}

__global__ __launch_bounds__(256, 3) void gnn_fused(
    const float* __restrict__ gf, const float* __restrict__ nf,
    const float* __restrict__ ef, const void* __restrict__ nmask_raw,
    const float* __restrict__ Wn, const float* __restrict__ bn,
    const float* __restrict__ We, const float* __restrict__ be,
    const float* __restrict__ Ws, const float* __restrict__ bs,
    const float* __restrict__ Wg, const float* __restrict__ bg,
    const float* __restrict__ Wc1, const float* __restrict__ bc1,
    const float* __restrict__ Wc2, const float* __restrict__ bc2,
    float* __restrict__ out)
{
    const int b = blockIdx.x;
    const int t = threadIdx.x;

    __shared__ __align__(16) float s_g[GD_];
    __shared__ int   s_mi[N_];
    __shared__ float s_emask[N_];
    __shared__ __align__(16) float s_ef[N_][ED_];
    __shared__ __align__(16) float s_efm[N_][ED_];
    __shared__ __align__(16) float s_nin[N_][32];
    __shared__ __align__(16) float s_hn[N_ + 1][HN_];
    __shared__ __align__(16) float s_he[N_][HE_];
    __shared__ __align__(16) float s_bias1[HN_];
    __shared__ __align__(16) float s_bias2[HE_];
    __shared__ float s_sc[N_];
    __shared__ float s_w[N_];
    __shared__ __align__(16) float s_tmp[256];
    __shared__ __align__(16) float s_aggf[HE_];
    __shared__ __align__(16) float s_hg[HG_];
    __shared__ __align__(16) float s_hc[HC_];

    const unsigned char* mb = (const unsigned char*)nmask_raw;
    int cnt = __syncthreads_count(mb[t] != 0);
    const bool is_u8 = (cnt > 96);

    if (t < GD_) s_g[t] = gf[b * GD_ + t];
    for (int idx = t; idx < N_ * ND_; idx += 256)
        s_nin[idx >> 4][idx & 15] = nf[b * N_ * ND_ + idx];
    for (int idx = t; idx < (N_ - 1) * ED_; idx += 256)
        s_ef[idx >> 3][idx & 7] = ef[b * (N_ - 1) * ED_ + idx];
    if (t < ED_) s_ef[N_ - 1][t] = 0.0f;
    if (t < HN_) s_hn[N_][t] = 0.0f;
    if (t < N_) {
        int mv = is_u8 ? (int)mb[b * N_ + t] : ((const int*)nmask_raw)[b * N_ + t];
        s_mi[t] = mv;
    }
    __syncthreads();

    if (t < N_)
        s_emask[t] = (t < N_ - 1 && s_mi[t] != 0 && s_mi[t + 1] != 0) ? 1.0f : 0.0f;
    __syncthreads();

    {
        int e = t >> 3, k = t & 7;
        s_efm[e][k] = s_ef[e][k] * s_emask[e];
    }
    {
        int j = t & 127;
        if (t < 128) {
            float v = bn[j];
#pragma unroll
            for (int k = 0; k < GD_; ++k)
                v += s_g[k] * Wn[(ND_ + 2 * ED_ + k) * HN_ + j];
            s_bias1[j] = v;
        } else {
            float v = be[j];
#pragma unroll
            for (int k = 0; k < GD_; ++k)
                v += s_g[k] * We[(ED_ + 2 * HN_ + k) * HE_ + j];
            s_bias2[j] = v;
        }
    }
    __syncthreads();

    for (int idx = t; idx < N_ * 16; idx += 256) {
        int n = idx >> 4, kk = idx & 15;
        if (kk < 8) s_nin[n][16 + kk]       = (n > 0)      ? s_efm[n - 1][kk] : 0.0f;
        else        s_nin[n][24 + (kk - 8)] = (n < N_ - 1) ? s_efm[n][kk - 8] : 0.0f;
    }
    __syncthreads();

    const int jg = t & 31, rg = t >> 5;
    const int c4 = jg * 4, r4 = rg * 4;

    {
        float acc[4][4];
#pragma unroll
        for (int r = 0; r < 4; ++r)
#pragma unroll
            for (int c = 0; c < 4; ++c) acc[r][c] = s_bias1[c4 + c];
        const float* i0 = &s_nin[r4 + 0][0];
        const float* i1 = &s_nin[r4 + 1][0];
        const float* i2 = &s_nin[r4 + 2][0];
        const float* i3 = &s_nin[r4 + 3][0];
#pragma unroll
        for (int k = 0; k < 32; k += 4)
            tile_fma_4x4(acc, i0, i1, i2, i3, k, Wn, k, c4);
#pragma unroll
        for (int r = 0; r < 4; ++r)
#pragma unroll
            for (int c = 0; c < 4; ++c)
                s_hn[r4 + r][c4 + c] = fmaxf(acc[r][c], 0.0f);
    }
    __syncthreads();

    {
        float acc[4][4];
#pragma unroll
        for (int r = 0; r < 4; ++r)
#pragma unroll
            for (int c = 0; c < 4; ++c) acc[r][c] = s_bias2[c4 + c];
        {
            const float* i0 = &s_ef[r4 + 0][0];
            const float* i1 = &s_ef[r4 + 1][0];
            const float* i2 = &s_ef[r4 + 2][0];
            const float* i3 = &s_ef[r4 + 3][0];
#pragma unroll
            for (int k = 0; k < 8; k += 4)
                tile_fma_4x4(acc, i0, i1, i2, i3, k, We, k, c4);
        }
        {
            const float* i0 = &s_hn[r4 + 0][0];
            const float* i1 = &s_hn[r4 + 1][0];
            const float* i2 = &s_hn[r4 + 2][0];
            const float* i3 = &s_hn[r4 + 3][0];
#pragma unroll 4
            for (int k = 0; k < 128; k += 4)
                tile_fma_4x4(acc, i0, i1, i2, i3, k, We, 8 + k, c4);
        }
        {
            const float* i0 = &s_hn[r4 + 1][0];
            const float* i1 = &s_hn[r4 + 2][0];
            const float* i2 = &s_hn[r4 + 3][0];
            const float* i3 = &s_hn[r4 + 4][0];
#pragma unroll 4
            for (int k = 0; k < 128; k += 4)
                tile_fma_4x4(acc, i0, i1, i2, i3, k, We, 136 + k, c4);
        }
#pragma unroll
        for (int r = 0; r < 4; ++r)
#pragma unroll
            for (int c = 0; c < 4; ++c)
                s_he[r4 + r][c4 + c] = fmaxf(acc[r][c], 0.0f);
    }
    __syncthreads();

    {
        int c = t & 7, e = t >> 3;
        const float* he = &s_he[e][0];
        float p = 0.0f;
#pragma unroll
        for (int j0 = 0; j0 < 16; j0 += 4) {
            float4 h = *(const float4*)&he[c * 16 + j0];
            float4 wv = *(const float4*)&Ws[c * 16 + j0];
            p += h.x * wv.x + h.y * wv.y + h.z * wv.z + h.w * wv.w;
        }
        p += __shfl_xor(p, 1);
        p += __shfl_xor(p, 2);
        p += __shfl_xor(p, 4);
        if (c == 0) s_sc[e] = p + bs[0];
    }
    __syncthreads();
    if (t < 64) {
        float v = -INFINITY;
        if (t < N_ - 1)
            v = s_sc[t] * s_emask[t] + (1.0f - s_emask[t]) * (-1e9f);
        float m = v;
#pragma unroll
        for (int d = 32; d >= 1; d >>= 1) m = fmaxf(m, __shfl_xor(m, d));
        float e_ = (t < N_ - 1) ? expf(v - m) : 0.0f;
        float ssum = e_;
#pragma unroll
        for (int d = 32; d >= 1; d >>= 1) ssum += __shfl_xor(ssum, d);
        if (t < N_) s_w[t] = (t < N_ - 1) ? (e_ / ssum) : 0.0f;
    }
    __syncthreads();

    {
        int j = t & 127, half = t >> 7;
        float p = 0.0f;
#pragma unroll
        for (int e = 0; e < 16; ++e) {
            int ee = half * 16 + e;
            p += s_he[ee][j] * s_w[ee];
        }
        s_tmp[half * 128 + j] = p;
    }
    __syncthreads();
    if (t < 128) s_aggf[t] = s_tmp[t] + s_tmp[128 + t];
    __syncthreads();

    {
        int j = t & 127, half = t >> 7;
        float p = 0.0f;
        for (int k = half * 64; k < half * 64 + 64; ++k)
            p += s_aggf[k] * Wg[k * HG_ + j];
        s_tmp[half * 128 + j] = p;
    }
    __syncthreads();
    if (t < 128) s_hg[t] = fmaxf(s_tmp[t] + s_tmp[128 + t] + bg[t], 0.0f);
    __syncthreads();

    {
        int j = t & 63, q = t >> 6;
        float p = 0.0f;
        for (int k = q * 32; k < q * 32 + 32; ++k)
            p += s_hg[k] * Wc1[k * HC_ + j];
        s_tmp[q * 64 + j] = p;
    }
    __syncthreads();
    if (t < 64)
        s_hc[t] = fmaxf(s_tmp[t] + s_tmp[64 + t] + s_tmp[128 + t] + s_tmp[192 + t] + bc1[t], 0.0f);
    __syncthreads();

    if (t < 64) {
        float p = s_hc[t] * Wc2[t];
#pragma unroll
        for (int d = 32; d >= 1; d >>= 1) p += __shfl_xor(p, d);
        if (t == 0) out[b] = p + bc2[0];
    }
}

extern "C" void kernel_launch(void* const* d_in, const int* in_sizes, int n_in,
                              void* d_out, int out_size, void* d_ws, size_t ws_size,
                              hipStream_t stream) {
    const float* gf  = (const float*)d_in[0];
    const float* nf  = (const float*)d_in[1];
    const float* ef  = (const float*)d_in[2];
    const void*  nm  = d_in[3];
    const float* Wn  = (const float*)d_in[4];
    const float* bn  = (const float*)d_in[5];
    const float* We  = (const float*)d_in[6];
    const float* be  = (const float*)d_in[7];
    const float* Ws  = (const float*)d_in[8];
    const float* bs  = (const float*)d_in[9];
    const float* Wg  = (const float*)d_in[10];
    const float* bg  = (const float*)d_in[11];
    const float* Wc1 = (const float*)d_in[12];
    const float* bc1 = (const float*)d_in[13];
    const float* Wc2 = (const float*)d_in[14];
    const float* bc2 = (const float*)d_in[15];
    float* out = (float*)d_out;

    const int B = in_sizes[0] / GD_;

    if (ws_size >= (size_t)WS_BYTES && B >= 2) {
        prep_weights<<<20, 256, 0, stream>>>(Wn, We, (unsigned short*)d_ws);
        const int NB = (B + 1) / 2;
        gnn_mfma2<<<NB, 256, 0, stream>>>(gf, nf, ef, nm, Wn, bn, We, be, Ws, bs,
                                          Wg, bg, Wc1, bc1, Wc2, bc2,
                                          (const unsigned short*)d_ws, out, B);
    } else {
        gnn_fused<<<B, 256, 0, stream>>>(gf, nf, ef, nm, Wn, bn, We, be, Ws, bs,
                                         Wg, bg, Wc1, bc1, Wc2, bc2, out);
    }
}